// Round 2
// baseline (156.660 us; speedup 1.0000x reference)
//
#include <hip/hip_runtime.h>

typedef _Float16 half_t;
typedef __attribute__((ext_vector_type(8))) _Float16 half8;   // MFMA A/B frag (4 VGPRs)
typedef __attribute__((ext_vector_type(4))) float f32x4;      // MFMA C/D frag

#define NPOLY 16384   // B*N = 16*1024
#define PPTS  32
#define CIN   9

__device__ __forceinline__ half8 ld8(const half_t* p){
    return *reinterpret_cast<const half8*>(p);
}
__device__ __forceinline__ half8 h8zero(){
    half8 v;
    #pragma unroll
    for (int j = 0; j < 8; j++) v[j] = (half_t)0.f;
    return v;
}
__device__ __forceinline__ f32x4 MFMA(half8 a, half8 b, f32x4 c){
    return __builtin_amdgcn_mfma_f32_16x16x32_f16(a, b, c, 0, 0, 0);
}
// Fragment layouts (measured, learn_hip m89/m120; dtype-independent):
//   A[m][k]: m = lane&15 (+16*mt), k = (lane>>4)*8 + j (+32*ks)
//   B[k][n]: n = lane&15 (+16*nt), k = (lane>>4)*8 + j (+32*ks)
//   C/D[row][col]: col = lane&15 (+16*nt), row = (lane>>4)*4 + r (+16*mt)

// =====================================================================
// Kernel 1: pre-MLP -> mask -> maxpool -> concat -> l1 -> l2 -> masked max
// one wave per polyline iteration (4 polylines/wave), weights frag-staged in LDS
// =====================================================================
__global__ __launch_bounds__(256, 2) void k_encoder(
    const float* __restrict__ px,        // [NPOLY][32][9] fp32
    const int*   __restrict__ pmask,     // [NPOLY][32] int32 0/1
    const float* __restrict__ w_pre, const float* __restrict__ b_pre,
    const float* __restrict__ g_pre, const float* __restrict__ be_pre,
    const float* __restrict__ rm_pre, const float* __restrict__ rv_pre,
    const float* __restrict__ w_m1, const float* __restrict__ b_m1,
    const float* __restrict__ g_m1, const float* __restrict__ be_m1,
    const float* __restrict__ rm_m1, const float* __restrict__ rv_m1,
    const float* __restrict__ w_m2, const float* __restrict__ b_m2,
    const float* __restrict__ g_m2, const float* __restrict__ be_m2,
    const float* __restrict__ rm_m2, const float* __restrict__ rv_m2,
    float* __restrict__ feat, int* __restrict__ valid)
{
    // weight frags (f16): pre = frags 0..3 (nt), m1 = 4..19 (ks*4+nt), m2 = 20..27
    __shared__ __align__(16) half_t lds_w[28 * 512];
    __shared__ __align__(16) half_t fg[4][32 * 72];   // per-wave f/g A-tile, 32 rows x 72 (64 + 8 pad)
    __shared__ __align__(16) half_t pooledb[4][64];
    __shared__ int maskb[4][32];

    const int tid  = threadIdx.x;
    const int wave = tid >> 6, lane = tid & 63, l15 = lane & 15, q = lane >> 4;

    // ---- stage weight fragments, fp32 -> f16 (block-cooperative, once) ----
    for (int s = tid; s < 28 * 64; s += 256) {
        int frag = s >> 6, ln = s & 63;
        const float* W; int K, ks, nt;
        if (frag < 4)       { W = w_pre; K = CIN; ks = 0; nt = frag; }
        else if (frag < 20) { W = w_m1;  K = 128; int f = frag - 4;  ks = f >> 2; nt = f & 3; }
        else                { W = w_m2;  K = 64;  int f = frag - 20; ks = f >> 2; nt = f & 3; }
        int col = nt * 16 + (ln & 15);
        int kb  = ks * 32 + ((ln >> 4) << 3);
        half_t* dst = &lds_w[s * 8];
        #pragma unroll
        for (int j = 0; j < 8; j++) {
            int k  = kb + j;
            int ka = (k < K) ? k : 0;                 // clamp: keep address in-bounds
            float v = W[ka * 64 + col];               // all three W have 64 cols
            dst[j] = (k < K) ? (half_t)v : (half_t)0.f;
        }
    }
    __syncthreads();

    // ---- fold BN into affine: out = dot * sA[h] + sC[h], h = nt*16+l15 ----
    float sA0[4], sC0[4], sA1[4], sC1[4], sA2[4], sC2[4];
    #pragma unroll
    for (int nt = 0; nt < 4; nt++) {
        int h = nt * 16 + l15;
        float a;
        a = g_pre[h] * rsqrtf(rv_pre[h] + 1e-5f);
        sA0[nt] = a; sC0[nt] = (b_pre[h] - rm_pre[h]) * a + be_pre[h];
        a = g_m1[h] * rsqrtf(rv_m1[h] + 1e-5f);
        sA1[nt] = a; sC1[nt] = (b_m1[h] - rm_m1[h]) * a + be_m1[h];
        a = g_m2[h] * rsqrtf(rv_m2[h] + 1e-5f);
        sA2[nt] = a; sC2[nt] = (b_m2[h] - rm_m2[h]) * a + be_m2[h];
    }

    const int wgid = blockIdx.x * 4 + wave;
    for (int it = 0; it < 4; ++it) {
        const int n = wgid * 4 + it;

        // ---- mask -> LDS (wave-private; in-order DS pipe, no barrier needed) ----
        if (lane < 32) maskb[wave][lane] = pmask[n * PPTS + lane];

        // ---- x A-frags direct from global (K=9, zero-padded to 32) ----
        half8 xa[2];
        #pragma unroll
        for (int mt = 0; mt < 2; mt++) {
            const float* src = px + ((long)n * PPTS + l15 + 16 * mt) * CIN;
            half8 v = h8zero();
            if (q == 0) {
                #pragma unroll
                for (int j = 0; j < 8; j++) v[j] = (half_t)src[j];
            } else if (q == 1) {
                v[0] = (half_t)src[8];
            }
            xa[mt] = v;
        }

        // ---- pre layer: (32x32 zero-padded) @ (32x64) ----
        f32x4 acc[2][4];
        #pragma unroll
        for (int a_ = 0; a_ < 2; a_++)
            #pragma unroll
            for (int b_ = 0; b_ < 4; b_++) acc[a_][b_] = (f32x4){0.f, 0.f, 0.f, 0.f};

        #pragma unroll
        for (int nt = 0; nt < 4; nt++) {
            half8 b = ld8(&lds_w[(0 + nt) * 512 + lane * 8]);
            acc[0][nt] = MFMA(xa[0], b, acc[0][nt]);
            acc[1][nt] = MFMA(xa[1], b, acc[1][nt]);
        }

        float maskf[8];
        #pragma unroll
        for (int mt = 0; mt < 2; mt++)
            #pragma unroll
            for (int r = 0; r < 4; r++)
                maskf[mt * 4 + r] = maskb[wave][mt * 16 + q * 4 + r] ? 1.f : 0.f;

        // BN+ReLU+mask, write f into A-layout tile, track pooled max (all vals >= 0)
        float pm[4];
        #pragma unroll
        for (int nt = 0; nt < 4; nt++) {
            float m = 0.f;
            #pragma unroll
            for (int mt = 0; mt < 2; mt++)
                #pragma unroll
                for (int r = 0; r < 4; r++) {
                    float v = acc[mt][nt][r] * sA0[nt] + sC0[nt];
                    v = fmaxf(v, 0.f) * maskf[mt * 4 + r];
                    fg[wave][(mt * 16 + q * 4 + r) * 72 + nt * 16 + l15] = (half_t)v;
                    m = fmaxf(m, v);
                }
            m = fmaxf(m, __shfl_xor(m, 16));
            m = fmaxf(m, __shfl_xor(m, 32));
            pm[nt] = m;
        }
        {
            float pv = (q == 0) ? pm[0] : (q == 1) ? pm[1] : (q == 2) ? pm[2] : pm[3];
            pooledb[wave][lane] = (half_t)pv;   // col = q*16+l15 = lane
        }

        // ---- mlp l1: A = [f | pooled-bcast] (32x128) @ (128x64) ----
        f32x4 acc1[2][4];
        #pragma unroll
        for (int a_ = 0; a_ < 2; a_++)
            #pragma unroll
            for (int b_ = 0; b_ < 4; b_++) acc1[a_][b_] = (f32x4){0.f, 0.f, 0.f, 0.f};

        half8 pa0 = ld8(&pooledb[wave][q * 8]);        // ks=2 rows (same for all m)
        half8 pa1 = ld8(&pooledb[wave][32 + q * 8]);   // ks=3
        #pragma unroll
        for (int ks = 0; ks < 2; ks++) {
            half8 a0 = ld8(&fg[wave][l15 * 72 + ks * 32 + q * 8]);
            half8 a1 = ld8(&fg[wave][(l15 + 16) * 72 + ks * 32 + q * 8]);
            #pragma unroll
            for (int nt = 0; nt < 4; nt++) {
                half8 b = ld8(&lds_w[(4 + ks * 4 + nt) * 512 + lane * 8]);
                acc1[0][nt] = MFMA(a0, b, acc1[0][nt]);
                acc1[1][nt] = MFMA(a1, b, acc1[1][nt]);
            }
        }
        #pragma unroll
        for (int ks = 2; ks < 4; ks++) {
            half8 ap = (ks == 2) ? pa0 : pa1;
            #pragma unroll
            for (int nt = 0; nt < 4; nt++) {
                half8 b = ld8(&lds_w[(4 + ks * 4 + nt) * 512 + lane * 8]);
                acc1[0][nt] = MFMA(ap, b, acc1[0][nt]);
                acc1[1][nt] = MFMA(ap, b, acc1[1][nt]);
            }
        }
        // BN+ReLU (no mask between l1/l2), overwrite fg (prior reads precede in DS order)
        #pragma unroll
        for (int nt = 0; nt < 4; nt++)
            #pragma unroll
            for (int mt = 0; mt < 2; mt++)
                #pragma unroll
                for (int r = 0; r < 4; r++) {
                    float v = acc1[mt][nt][r] * sA1[nt] + sC1[nt];
                    v = fmaxf(v, 0.f);
                    fg[wave][(mt * 16 + q * 4 + r) * 72 + nt * 16 + l15] = (half_t)v;
                }

        // ---- mlp l2: (32x64) @ (64x64) ----
        f32x4 acc2[2][4];
        #pragma unroll
        for (int a_ = 0; a_ < 2; a_++)
            #pragma unroll
            for (int b_ = 0; b_ < 4; b_++) acc2[a_][b_] = (f32x4){0.f, 0.f, 0.f, 0.f};
        #pragma unroll
        for (int ks = 0; ks < 2; ks++) {
            half8 a0 = ld8(&fg[wave][l15 * 72 + ks * 32 + q * 8]);
            half8 a1 = ld8(&fg[wave][(l15 + 16) * 72 + ks * 32 + q * 8]);
            #pragma unroll
            for (int nt = 0; nt < 4; nt++) {
                half8 b = ld8(&lds_w[(20 + ks * 4 + nt) * 512 + lane * 8]);
                acc2[0][nt] = MFMA(a0, b, acc2[0][nt]);
                acc2[1][nt] = MFMA(a1, b, acc2[1][nt]);
            }
        }

        // BN+ReLU+mask, masked max over points -> feat
        float fm[4];
        #pragma unroll
        for (int nt = 0; nt < 4; nt++) {
            float m = 0.f;
            #pragma unroll
            for (int mt = 0; mt < 2; mt++)
                #pragma unroll
                for (int r = 0; r < 4; r++) {
                    float v = acc2[mt][nt][r] * sA2[nt] + sC2[nt];
                    v = fmaxf(v, 0.f) * maskf[mt * 4 + r];
                    m = fmaxf(m, v);
                }
            m = fmaxf(m, __shfl_xor(m, 16));
            m = fmaxf(m, __shfl_xor(m, 32));
            fm[nt] = m;
        }
        float fv = (q == 0) ? fm[0] : (q == 1) ? fm[1] : (q == 2) ? fm[2] : fm[3];
        feat[n * 64 + lane] = fv;   // coalesced: col = lane

        int lm = 0;
        #pragma unroll
        for (int j = 0; j < 8; j++) lm |= (maskf[j] != 0.f);
        unsigned long long bal = __ballot(lm);
        if (lane == 0) valid[n] = bal ? 1 : 0;
    }
}

// =====================================================================
// Kernel 2: out-MLPs  out = valid * ( relu(feat@W1 + b1) @ W2 + b2 )
// M = 16384 rows, 32 rows per wave
// =====================================================================
__global__ __launch_bounds__(256, 2) void k_out(
    const float* __restrict__ feat, const int* __restrict__ valid,
    const float* __restrict__ w1, const float* __restrict__ b1,
    const float* __restrict__ w2, const float* __restrict__ b2,
    float* __restrict__ out)
{
    __shared__ __align__(16) half_t lw[24 * 512];   // out1: frags 0..7, out2: 8..23
    __shared__ __align__(16) half_t qt[4][32 * 72];

    const int tid  = threadIdx.x;
    const int wave = tid >> 6, lane = tid & 63, l15 = lane & 15, q = lane >> 4;

    for (int s = tid; s < 24 * 64; s += 256) {
        int frag = s >> 6, ln = s & 63;
        const float* W; int stride, col, kb;
        if (frag < 8) { int ks = frag >> 2, nt = frag & 3; W = w1; stride = 64;
                        col = nt * 16 + (ln & 15); kb = ks * 32 + ((ln >> 4) << 3); }
        else          { int f = frag - 8; int ks = f >> 3, nt = f & 7; W = w2; stride = 128;
                        col = nt * 16 + (ln & 15); kb = ks * 32 + ((ln >> 4) << 3); }
        half_t* dst = &lw[s * 8];
        #pragma unroll
        for (int j = 0; j < 8; j++) dst[j] = (half_t)W[(kb + j) * stride + col];
    }
    __syncthreads();

    float bb1[4], bb2[8];
    #pragma unroll
    for (int nt = 0; nt < 4; nt++) bb1[nt] = b1[nt * 16 + l15];
    #pragma unroll
    for (int nt = 0; nt < 8; nt++) bb2[nt] = b2[nt * 16 + l15];

    const int n0 = (blockIdx.x * 4 + wave) * 32;

    // feat A-frags (fp32 -> f16)
    half8 af[2][2];
    #pragma unroll
    for (int mt = 0; mt < 2; mt++)
        #pragma unroll
        for (int ks = 0; ks < 2; ks++) {
            const float* src = feat + (n0 + l15 + 16 * mt) * 64 + ks * 32 + q * 8;
            half8 v;
            #pragma unroll
            for (int j = 0; j < 8; j++) v[j] = (half_t)src[j];
            af[mt][ks] = v;
        }

    f32x4 acc1[2][4];
    #pragma unroll
    for (int a_ = 0; a_ < 2; a_++)
        #pragma unroll
        for (int b_ = 0; b_ < 4; b_++) acc1[a_][b_] = (f32x4){0.f, 0.f, 0.f, 0.f};
    #pragma unroll
    for (int ks = 0; ks < 2; ks++)
        #pragma unroll
        for (int nt = 0; nt < 4; nt++) {
            half8 b = ld8(&lw[(ks * 4 + nt) * 512 + lane * 8]);
            acc1[0][nt] = MFMA(af[0][ks], b, acc1[0][nt]);
            acc1[1][nt] = MFMA(af[1][ks], b, acc1[1][nt]);
        }

    // relu(.+b1) -> q-tile (A-layout)
    #pragma unroll
    for (int nt = 0; nt < 4; nt++)
        #pragma unroll
        for (int mt = 0; mt < 2; mt++)
            #pragma unroll
            for (int r = 0; r < 4; r++) {
                float v = fmaxf(acc1[mt][nt][r] + bb1[nt], 0.f);
                qt[wave][(mt * 16 + q * 4 + r) * 72 + nt * 16 + l15] = (half_t)v;
            }

    f32x4 acc2[2][8];
    #pragma unroll
    for (int a_ = 0; a_ < 2; a_++)
        #pragma unroll
        for (int b_ = 0; b_ < 8; b_++) acc2[a_][b_] = (f32x4){0.f, 0.f, 0.f, 0.f};
    #pragma unroll
    for (int ks = 0; ks < 2; ks++) {
        half8 a0 = ld8(&qt[wave][l15 * 72 + ks * 32 + q * 8]);
        half8 a1 = ld8(&qt[wave][(l15 + 16) * 72 + ks * 32 + q * 8]);
        #pragma unroll
        for (int nt = 0; nt < 8; nt++) {
            half8 b = ld8(&lw[(8 + ks * 8 + nt) * 512 + lane * 8]);
            acc2[0][nt] = MFMA(a0, b, acc2[0][nt]);
            acc2[1][nt] = MFMA(a1, b, acc2[1][nt]);
        }
    }

    float vr[8];
    #pragma unroll
    for (int mt = 0; mt < 2; mt++)
        #pragma unroll
        for (int r = 0; r < 4; r++)
            vr[mt * 4 + r] = valid[n0 + mt * 16 + q * 4 + r] ? 1.f : 0.f;

    #pragma unroll
    for (int mt = 0; mt < 2; mt++)
        #pragma unroll
        for (int nt = 0; nt < 8; nt++)
            #pragma unroll
            for (int r = 0; r < 4; r++) {
                float v = (acc2[mt][nt][r] + bb2[nt]) * vr[mt * 4 + r];
                out[(long)(n0 + mt * 16 + q * 4 + r) * 128 + nt * 16 + l15] = v;
            }
}

extern "C" void kernel_launch(void* const* d_in, const int* in_sizes, int n_in,
                              void* d_out, int out_size, void* d_ws, size_t ws_size,
                              hipStream_t stream) {
    const float* px    = (const float*)d_in[0];
    const int*   pmask = (const int*)d_in[1];

    float* feat  = (float*)d_ws;                                   // 16384*64 fp32 = 4 MB
    int*   valid = (int*)((char*)d_ws + (size_t)NPOLY * 64 * 4);   // 64 KB

    k_encoder<<<dim3(1024), dim3(256), 0, stream>>>(
        px, pmask,
        (const float*)d_in[2],  (const float*)d_in[3],  (const float*)d_in[4],
        (const float*)d_in[5],  (const float*)d_in[6],  (const float*)d_in[7],
        (const float*)d_in[8],  (const float*)d_in[9],  (const float*)d_in[10],
        (const float*)d_in[11], (const float*)d_in[12], (const float*)d_in[13],
        (const float*)d_in[14], (const float*)d_in[15], (const float*)d_in[16],
        (const float*)d_in[17], (const float*)d_in[18], (const float*)d_in[19],
        feat, valid);

    k_out<<<dim3(128), dim3(256), 0, stream>>>(
        feat, valid,
        (const float*)d_in[20], (const float*)d_in[21],
        (const float*)d_in[22], (const float*)d_in[23],
        (float*)d_out);
}

// Round 3
// 141.044 us; speedup vs baseline: 1.1107x; 1.1107x over previous
//
#include <hip/hip_runtime.h>

typedef _Float16 half_t;
typedef __attribute__((ext_vector_type(8))) _Float16 half8;   // MFMA A/B frag (4 VGPRs)
typedef __attribute__((ext_vector_type(4))) float f32x4;      // MFMA C/D frag

#define NPOLY 16384   // B*N
#define PPTS  32
#define CIN   9

__device__ __forceinline__ half8 ld8(const half_t* p){
    return *reinterpret_cast<const half8*>(p);
}
__device__ __forceinline__ f32x4 MFMA(half8 a, half8 b, f32x4 c){
    return __builtin_amdgcn_mfma_f32_16x16x32_f16(a, b, c, 0, 0, 0);
}
// Fragment layouts (measured, learn_hip m89/m120; dtype-independent):
//   A[m][k]: m = lane&15 (+16*mt), k = (lane>>4)*8 + j (+32*ks)
//   B[k][n]: n = lane&15 (+16*nt), k = (lane>>4)*8 + j (+32*ks)
//   C/D[row][col]: col = lane&15 (+16*nt), row = (lane>>4)*4 + r (+16*mt)

// =====================================================================
// Fully fused: pre-MLP -> mask -> maxpool -> concat -> l1 -> l2 ->
// masked max -> out1(relu) -> out2 -> valid mask.
// Block = 256 threads (4 waves) = 16 polylines; wave w owns rows 4w..4w+3.
// BN folded: weights pre-scaled by sA at staging, sC via MFMA acc init.
// LDS 53.3 KB -> 3 blocks/CU.
// =====================================================================
__global__ __launch_bounds__(256, 3) void k_fused(
    const float* __restrict__ px,        // [NPOLY][32][9]
    const int*   __restrict__ pmask,     // [NPOLY][32]
    const float* __restrict__ w_pre, const float* __restrict__ b_pre,
    const float* __restrict__ g_pre, const float* __restrict__ be_pre,
    const float* __restrict__ rm_pre, const float* __restrict__ rv_pre,
    const float* __restrict__ w_m1, const float* __restrict__ b_m1,
    const float* __restrict__ g_m1, const float* __restrict__ be_m1,
    const float* __restrict__ rm_m1, const float* __restrict__ rv_m1,
    const float* __restrict__ w_m2, const float* __restrict__ b_m2,
    const float* __restrict__ g_m2, const float* __restrict__ be_m2,
    const float* __restrict__ rm_m2, const float* __restrict__ rv_m2,
    const float* __restrict__ w1, const float* __restrict__ b1,
    const float* __restrict__ w2, const float* __restrict__ b2,
    float* __restrict__ out)
{
    // encoder weight frags (f16, BN-scaled): pre 0..3, m1 4..19, m2 20..27
    __shared__ __align__(16) half_t lds_w[28 * 512];   // 28 KB
    __shared__ __align__(16) half_t fg[4][32 * 72];    // 18 KB per-wave f/g A-tiles
    __shared__ __align__(16) half_t pooledb[4][64];    // 0.5 KB
    __shared__ __align__(16) half_t ft[16 * 72];       // 2.25 KB feat A-tile (16 rows)
    __shared__ __align__(16) half_t qt[16 * 72];       // 2.25 KB out1 A-tile
    __shared__ int maskb[4][2][32];                    // 1 KB (double-buffered)
    __shared__ int validb[16];

    const int tid  = threadIdx.x;
    const int wave = tid >> 6, lane = tid & 63, l15 = lane & 15, q = lane >> 4;

    // ---- stage encoder weights, fp32 -> f16, folding BN scale sA ----
    for (int s = tid; s < 28 * 64; s += 256) {
        int frag = s >> 6, ln = s & 63;
        const float *W, *G, *RV; int K, ks, nt;
        if (frag < 4)       { W = w_pre; G = g_pre; RV = rv_pre; K = CIN; ks = 0; nt = frag; }
        else if (frag < 20) { W = w_m1;  G = g_m1;  RV = rv_m1;  K = 128; int f = frag - 4;  ks = f >> 2; nt = f & 3; }
        else                { W = w_m2;  G = g_m2;  RV = rv_m2;  K = 64;  int f = frag - 20; ks = f >> 2; nt = f & 3; }
        int col = nt * 16 + (ln & 15);
        int kb  = ks * 32 + ((ln >> 4) << 3);
        float sA = G[col] * rsqrtf(RV[col] + 1e-5f);
        half_t* dst = &lds_w[s * 8];
        #pragma unroll
        for (int j = 0; j < 8; j++) {
            int k  = kb + j;
            int ka = (k < K) ? k : 0;
            float v = W[ka * 64 + col] * sA;
            dst[j] = (k < K) ? (half_t)v : (half_t)0.f;
        }
    }

    // ---- per-lane BN bias consts (go into MFMA acc init), h = nt*16+l15 ----
    float sC0[4], sC1[4], sC2[4];
    #pragma unroll
    for (int nt = 0; nt < 4; nt++) {
        int h = nt * 16 + l15; float a;
        a = g_pre[h] * rsqrtf(rv_pre[h] + 1e-5f); sC0[nt] = (b_pre[h] - rm_pre[h]) * a + be_pre[h];
        a = g_m1[h]  * rsqrtf(rv_m1[h]  + 1e-5f); sC1[nt] = (b_m1[h]  - rm_m1[h])  * a + be_m1[h];
        a = g_m2[h]  * rsqrtf(rv_m2[h]  + 1e-5f); sC2[nt] = (b_m2[h]  - rm_m2[h])  * a + be_m2[h];
    }

    const int nbase = blockIdx.x * 16 + wave * 4;

    // ---- prefetch iter 0 x (lanes q<2) and mask (lanes 32..63) ----
    float xr[2][8];
    #pragma unroll
    for (int mt = 0; mt < 2; mt++) {
        const float* src = px + ((long)nbase * PPTS + l15 + 16 * mt) * CIN;
        if (q == 0) {
            #pragma unroll
            for (int j = 0; j < 8; j++) xr[mt][j] = src[j];
        } else if (q == 1) {
            xr[mt][0] = src[8];
        }
    }
    if (lane >= 32) maskb[wave][0][lane - 32] = pmask[nbase * PPTS + (lane - 32)];

    __syncthreads();   // weights staged

    #pragma unroll
    for (int it = 0; it < 4; ++it) {
        const int n = nbase + it;

        // ---- issue next-iteration prefetch loads (consumed at iter end) ----
        float xn[2][8]; int mnext = 0;
        if (it < 3) {
            #pragma unroll
            for (int mt = 0; mt < 2; mt++) {
                const float* src = px + ((long)(n + 1) * PPTS + l15 + 16 * mt) * CIN;
                if (q == 0) {
                    #pragma unroll
                    for (int j = 0; j < 8; j++) xn[mt][j] = src[j];
                } else if (q == 1) {
                    xn[mt][0] = src[8];
                }
            }
            if (lane >= 32) mnext = pmask[(n + 1) * PPTS + (lane - 32)];
        }

        // ---- build x A-frags (K=9 zero-padded to 32) ----
        half8 xa[2];
        #pragma unroll
        for (int mt = 0; mt < 2; mt++) {
            half8 v;
            #pragma unroll
            for (int j = 0; j < 8; j++) v[j] = (half_t)0.f;
            if (q == 0) {
                #pragma unroll
                for (int j = 0; j < 8; j++) v[j] = (half_t)xr[mt][j];
            } else if (q == 1) {
                v[0] = (half_t)xr[mt][0];
            }
            xa[mt] = v;
        }

        // ---- pre layer: acc init = sC0 (BN bias) ----
        f32x4 acc[2][4];
        #pragma unroll
        for (int mt = 0; mt < 2; mt++)
            #pragma unroll
            for (int nt = 0; nt < 4; nt++)
                #pragma unroll
                for (int r = 0; r < 4; r++) acc[mt][nt][r] = sC0[nt];

        #pragma unroll
        for (int nt = 0; nt < 4; nt++) {
            half8 b = ld8(&lds_w[nt * 512 + lane * 8]);
            acc[0][nt] = MFMA(xa[0], b, acc[0][nt]);
            acc[1][nt] = MFMA(xa[1], b, acc[1][nt]);
        }

        float maskf[8];
        #pragma unroll
        for (int mt = 0; mt < 2; mt++)
            #pragma unroll
            for (int r = 0; r < 4; r++)
                maskf[mt * 4 + r] = maskb[wave][it & 1][mt * 16 + q * 4 + r] ? 1.f : 0.f;

        // ReLU+mask, write masked f into A-tile, track pooled max (vals >= 0)
        float pm[4];
        #pragma unroll
        for (int nt = 0; nt < 4; nt++) {
            float m = 0.f;
            #pragma unroll
            for (int mt = 0; mt < 2; mt++)
                #pragma unroll
                for (int r = 0; r < 4; r++) {
                    float v = fmaxf(acc[mt][nt][r], 0.f) * maskf[mt * 4 + r];
                    fg[wave][(mt * 16 + q * 4 + r) * 72 + nt * 16 + l15] = (half_t)v;
                    m = fmaxf(m, v);
                }
            m = fmaxf(m, __shfl_xor(m, 16));
            m = fmaxf(m, __shfl_xor(m, 32));
            pm[nt] = m;
        }
        {
            float pv = (q == 0) ? pm[0] : (q == 1) ? pm[1] : (q == 2) ? pm[2] : pm[3];
            pooledb[wave][lane] = (half_t)pv;   // col = q*16+l15 = lane
        }

        // ---- l1: A = [f | pooled-bcast] (32x128) @ (128x64), acc init sC1 ----
        f32x4 acc1[2][4];
        #pragma unroll
        for (int mt = 0; mt < 2; mt++)
            #pragma unroll
            for (int nt = 0; nt < 4; nt++)
                #pragma unroll
                for (int r = 0; r < 4; r++) acc1[mt][nt][r] = sC1[nt];

        half8 pa0 = ld8(&pooledb[wave][q * 8]);
        half8 pa1 = ld8(&pooledb[wave][32 + q * 8]);
        #pragma unroll
        for (int ks = 0; ks < 2; ks++) {
            half8 a0 = ld8(&fg[wave][l15 * 72 + ks * 32 + q * 8]);
            half8 a1 = ld8(&fg[wave][(l15 + 16) * 72 + ks * 32 + q * 8]);
            #pragma unroll
            for (int nt = 0; nt < 4; nt++) {
                half8 b = ld8(&lds_w[(4 + ks * 4 + nt) * 512 + lane * 8]);
                acc1[0][nt] = MFMA(a0, b, acc1[0][nt]);
                acc1[1][nt] = MFMA(a1, b, acc1[1][nt]);
            }
        }
        #pragma unroll
        for (int ks = 2; ks < 4; ks++) {
            half8 ap = (ks == 2) ? pa0 : pa1;
            #pragma unroll
            for (int nt = 0; nt < 4; nt++) {
                half8 b = ld8(&lds_w[(4 + ks * 4 + nt) * 512 + lane * 8]);
                acc1[0][nt] = MFMA(ap, b, acc1[0][nt]);
                acc1[1][nt] = MFMA(ap, b, acc1[1][nt]);
            }
        }
        // ReLU only (mask not needed between l1/l2), overwrite fg
        #pragma unroll
        for (int nt = 0; nt < 4; nt++)
            #pragma unroll
            for (int mt = 0; mt < 2; mt++)
                #pragma unroll
                for (int r = 0; r < 4; r++) {
                    float v = fmaxf(acc1[mt][nt][r], 0.f);
                    fg[wave][(mt * 16 + q * 4 + r) * 72 + nt * 16 + l15] = (half_t)v;
                }

        // ---- l2: (32x64) @ (64x64), acc init sC2 ----
        f32x4 acc2[2][4];
        #pragma unroll
        for (int mt = 0; mt < 2; mt++)
            #pragma unroll
            for (int nt = 0; nt < 4; nt++)
                #pragma unroll
                for (int r = 0; r < 4; r++) acc2[mt][nt][r] = sC2[nt];
        #pragma unroll
        for (int ks = 0; ks < 2; ks++) {
            half8 a0 = ld8(&fg[wave][l15 * 72 + ks * 32 + q * 8]);
            half8 a1 = ld8(&fg[wave][(l15 + 16) * 72 + ks * 32 + q * 8]);
            #pragma unroll
            for (int nt = 0; nt < 4; nt++) {
                half8 b = ld8(&lds_w[(20 + ks * 4 + nt) * 512 + lane * 8]);
                acc2[0][nt] = MFMA(a0, b, acc2[0][nt]);
                acc2[1][nt] = MFMA(a1, b, acc2[1][nt]);
            }
        }

        // ReLU+mask, masked max over points -> feat row into ft tile (f16)
        float fm[4];
        #pragma unroll
        for (int nt = 0; nt < 4; nt++) {
            float m = 0.f;
            #pragma unroll
            for (int mt = 0; mt < 2; mt++)
                #pragma unroll
                for (int r = 0; r < 4; r++) {
                    float v = fmaxf(acc2[mt][nt][r], 0.f) * maskf[mt * 4 + r];
                    m = fmaxf(m, v);
                }
            m = fmaxf(m, __shfl_xor(m, 16));
            m = fmaxf(m, __shfl_xor(m, 32));
            fm[nt] = m;
        }
        float fv = (q == 0) ? fm[0] : (q == 1) ? fm[1] : (q == 2) ? fm[2] : fm[3];
        ft[(wave * 4 + it) * 72 + lane] = (half_t)fv;   // row = 4w+it, col = lane

        int lm = 0;
        #pragma unroll
        for (int j = 0; j < 8; j++) lm |= (maskf[j] != 0.f);
        unsigned long long bal = __ballot(lm);
        if (lane == 0) validb[wave * 4 + it] = bal ? 1 : 0;

        // ---- commit prefetch for next iteration ----
        if (it < 3) {
            if (lane >= 32) maskb[wave][(it + 1) & 1][lane - 32] = mnext;
            #pragma unroll
            for (int mt = 0; mt < 2; mt++)
                #pragma unroll
                for (int j = 0; j < 8; j++) xr[mt][j] = xn[mt][j];
        }
    }

    // =============== out-MLP stage (M=16 rows per block) ===============
    // B-frags straight from global (L2-resident; no LDS staging) — issue
    // loads before the barrier so latency overlaps wave arrival.
    float bb1 = b1[wave * 16 + l15];
    half8 bw1[2];
    #pragma unroll
    for (int ks = 0; ks < 2; ks++)
        #pragma unroll
        for (int j = 0; j < 8; j++)
            bw1[ks][j] = (half_t)w1[(ks * 32 + q * 8 + j) * 64 + wave * 16 + l15];

    float bb2[2];
    half8 bw2[2][2];   // [ks][nn]
    #pragma unroll
    for (int nn = 0; nn < 2; nn++) {
        int c = (wave * 2 + nn) * 16 + l15;
        bb2[nn] = b2[c];
        #pragma unroll
        for (int ks = 0; ks < 2; ks++)
            #pragma unroll
            for (int j = 0; j < 8; j++)
                bw2[ks][nn][j] = (half_t)w2[(ks * 32 + q * 8 + j) * 128 + c];
    }

    __syncthreads();   // ft + validb complete

    // out1: wave w computes cols w*16..w*16+15
    f32x4 o1;
    #pragma unroll
    for (int r = 0; r < 4; r++) o1[r] = bb1;
    #pragma unroll
    for (int ks = 0; ks < 2; ks++) {
        half8 a = ld8(&ft[l15 * 72 + ks * 32 + q * 8]);
        o1 = MFMA(a, bw1[ks], o1);
    }
    #pragma unroll
    for (int r = 0; r < 4; r++) {
        float v = fmaxf(o1[r], 0.f);
        qt[(q * 4 + r) * 72 + wave * 16 + l15] = (half_t)v;
    }

    __syncthreads();   // qt complete

    // out2: wave w computes cols (2w)*16 .. (2w+1)*16+15
    f32x4 o2[2];
    #pragma unroll
    for (int nn = 0; nn < 2; nn++)
        #pragma unroll
        for (int r = 0; r < 4; r++) o2[nn][r] = bb2[nn];
    #pragma unroll
    for (int ks = 0; ks < 2; ks++) {
        half8 a = ld8(&qt[l15 * 72 + ks * 32 + q * 8]);
        o2[0] = MFMA(a, bw2[ks][0], o2[0]);
        o2[1] = MFMA(a, bw2[ks][1], o2[1]);
    }
    #pragma unroll
    for (int r = 0; r < 4; r++) {
        float vr = validb[q * 4 + r] ? 1.f : 0.f;
        long rowg = (long)(blockIdx.x * 16 + q * 4 + r);
        out[rowg * 128 + (wave * 2 + 0) * 16 + l15] = o2[0][r] * vr;
        out[rowg * 128 + (wave * 2 + 1) * 16 + l15] = o2[1][r] * vr;
    }
}

extern "C" void kernel_launch(void* const* d_in, const int* in_sizes, int n_in,
                              void* d_out, int out_size, void* d_ws, size_t ws_size,
                              hipStream_t stream) {
    (void)in_sizes; (void)n_in; (void)out_size; (void)d_ws; (void)ws_size;
    k_fused<<<dim3(NPOLY / 16), dim3(256), 0, stream>>>(
        (const float*)d_in[0], (const int*)d_in[1],
        (const float*)d_in[2],  (const float*)d_in[3],  (const float*)d_in[4],
        (const float*)d_in[5],  (const float*)d_in[6],  (const float*)d_in[7],
        (const float*)d_in[8],  (const float*)d_in[9],  (const float*)d_in[10],
        (const float*)d_in[11], (const float*)d_in[12], (const float*)d_in[13],
        (const float*)d_in[14], (const float*)d_in[15], (const float*)d_in[16],
        (const float*)d_in[17], (const float*)d_in[18], (const float*)d_in[19],
        (const float*)d_in[20], (const float*)d_in[21],
        (const float*)d_in[22], (const float*)d_in[23],
        (float*)d_out);
}